// Round 1
// baseline (535.622 us; speedup 1.0000x reference)
//
#include <hip/hip_runtime.h>
#include <hip/hip_bf16.h>

#define DD 80
#define CIN 32
#define PLANE (DD*DD)        // 6400
#define VOX (DD*DD*DD)       // 512000
#define NPTS 200000

typedef __attribute__((ext_vector_type(8))) short bf16x8;
typedef __attribute__((ext_vector_type(4))) float floatx4;

static __device__ __forceinline__ short f2bf(float v) {
    __hip_bfloat16 b = __float2bfloat16(v);
    return *(short*)&b;
}

// async global->LDS 16B copy: lane's 16B lands at ldsbase + lane*16 (wave-uniform base)
static __device__ __forceinline__ void async_copy16(void* lds, const void* g) {
    __builtin_amdgcn_global_load_lds(
        (const __attribute__((address_space(1))) unsigned int*)g,
        (__attribute__((address_space(3))) unsigned int*)lds, 16, 0, 0);
}

// ---------------- K0: convert/permute all weights to bf16 ----------------
__global__ void convert_weights(const float* __restrict__ w2,
                                const float* __restrict__ w_p1,
                                const float* __restrict__ w_p2,
                                const float* __restrict__ w_p3,
                                const float* __restrict__ w_e1,
                                short* __restrict__ wpb, short* __restrict__ w1b,
                                short* __restrict__ w2b, short* __restrict__ w3b,
                                short* __restrict__ wc1) {
    int i = blockIdx.x * 256 + threadIdx.x;      // total 264192
    if (i < 110592) {
        int oc = i / 1728, j = i - oc * 1728;
        int off = j >> 6, ic = j & 63;
        wpb[i] = f2bf(w2[oc * 1728 + ic * 27 + off]);
    } else if (i < 110592 + 16384) {
        int j = i - 110592;
        w1b[j] = f2bf(w_p1[j]);
    } else if (i < 110592 + 16384 + 65536) {
        int j = i - 110592 - 16384;
        w2b[j] = f2bf(w_p2[j]);
    } else if (i < 110592 + 16384 + 65536 + 16384) {
        int j = i - 110592 - 16384 - 65536;
        w3b[j] = f2bf(w_p3[j]);
    } else if (i < 110592 + 16384 + 65536 + 16384 + 55296) {
        int j = i - (110592 + 16384 + 65536 + 16384);   // [off][oc][ic]
        int off = j / 2048, r = j - off * 2048;
        int oc = r >> 5, ic = r & 31;
        wc1[j] = f2bf(w_e1[(oc * 32 + ic) * 27 + off]);
    }
}

// ---------------- K0b: transpose img (32,VOX) fp32 -> img_t [vox][32] bf16 ----------------
__global__ __launch_bounds__(256) void transpose_img(
    const float* __restrict__ img, short* __restrict__ img_t)
{
    int v = blockIdx.x * 256 + threadIdx.x;
    if (v >= VOX) return;
    short row[32];
    #pragma unroll
    for (int ic = 0; ic < 32; ic++)
        row[ic] = f2bf(img[(size_t)ic * VOX + v]);
    int4* dst = (int4*)(img_t + (size_t)v * 32);
    #pragma unroll
    for (int c = 0; c < 4; c++) dst[c] = ((int4*)row)[c];
}

// ---------------- K1: conv1 via implicit-GEMM MFMA, async LDS staging ----------------
__global__ __launch_bounds__(256) void conv1_mfma(
    const short* __restrict__ img_t, const short* __restrict__ wc1,
    const float* __restrict__ b1, const short* __restrict__ zeros,
    short* __restrict__ f1)
{
    __shared__ short Alds[3072 * 16 / 2];   // 48 KB

    const int bh = blockIdx.x;
    const int d = bh / DD, h = bh - d * DD;
    const int tid = threadIdx.x;
    const int w = tid >> 6, lane = tid & 63;
    const int q = lane >> 4, lc = lane & 15;

    for (int i = 0; i < 12; i++) {
        int s = (w * 12 + i) * 64 + lane;      // slot 0..3071
        int row = s >> 2, c = s & 3;
        int cs = c ^ (row & 3);                // swizzled source chunk
        int rr = row / 82, v = row - rr * 82;
        int dz = rr / 3, dyy = rr - dz * 3;
        int zz = d + dz - 1, yy = h + dyy - 1, ww = v - 1;
        const short* src = zeros;
        if (row < 738 && (unsigned)zz < DD && (unsigned)yy < DD && (unsigned)ww < DD)
            src = img_t + ((size_t)(zz * PLANE + yy * DD + ww)) * 32 + cs * 8;
        async_copy16(&Alds[(w * 12 + i) * 512], src);
    }
    __syncthreads();

    floatx4 acc[5];
    #pragma unroll
    for (int mt = 0; mt < 5; mt++) acc[mt] = (floatx4){0.f, 0.f, 0.f, 0.f};

    #pragma unroll 3
    for (int off = 0; off < 27; ++off) {
        const int dz = off / 9, rem = off - dz * 9;
        const int dy = rem / 3, dx = rem - dy * 3;
        const int rr = dz * 3 + dy;
        bf16x8 bfr = *(const bf16x8*)(wc1 + ((off * 64 + w * 16 + lc) << 5) + q * 8);
        #pragma unroll
        for (int mt = 0; mt < 5; mt++) {
            const int vv = rr * 82 + mt * 16 + lc + dx;
            bf16x8 afr = *(const bf16x8*)(&Alds[vv * 32 + ((q ^ (vv & 3)) << 3)]);
            acc[mt] = __builtin_amdgcn_mfma_f32_16x16x32_bf16(afr, bfr, acc[mt], 0, 0, 0);
        }
    }

    const int oc = w * 16 + lc;
    const float bias = b1[oc];
    const size_t vbase = (size_t)(d * DD + h) * DD;
    #pragma unroll
    for (int mt = 0; mt < 5; mt++) {
        #pragma unroll
        for (int r = 0; r < 4; r++) {
            const int m = mt * 16 + q * 4 + r;
            float v = acc[mt][r] + bias;
            f1[(vbase + m) * 64 + oc] = f2bf(v > 0.f ? v : 0.f);
        }
    }
}

// ---------------- binning: counting sort of points into 8^3 spatial cells ----------------
// 10x10x10 = 1000 cells, ~200 pts/cell. A 256-pt conv2 block then spans ~1.3 cells,
// shrinking its gather footprint from ~880 KB (random) to ~160 KB (compact, L2-resident).
__global__ __launch_bounds__(256) void hist_cells(
    const int* __restrict__ c0, const int* __restrict__ c1, const int* __restrict__ c2,
    int* __restrict__ hist)
{
    int p = blockIdx.x * 256 + threadIdx.x;
    if (p >= NPTS) return;
    int cell = (c0[p] >> 3) * 100 + (c1[p] >> 3) * 10 + (c2[p] >> 3);
    atomicAdd(&hist[cell], 1);
}

__global__ __launch_bounds__(1024) void scan_cells(int* __restrict__ hist) {
    __shared__ int a[1024], b[1024];
    const int t = threadIdx.x;
    int self = (t < 1000) ? hist[t] : 0;
    a[t] = self;
    __syncthreads();
    int* src = a; int* dst = b;
    for (int d = 1; d < 1024; d <<= 1) {
        int v = src[t];
        if (t >= d) v += src[t - d];
        dst[t] = v;
        __syncthreads();
        int* tmp = src; src = dst; dst = tmp;
    }
    if (t < 1000) hist[t] = src[t] - self;   // exclusive scan, in place
}

__global__ __launch_bounds__(256) void scatter_points(
    const int* __restrict__ c0, const int* __restrict__ c1, const int* __restrict__ c2,
    int* __restrict__ cellofs, int* __restrict__ perm, int* __restrict__ pcoord)
{
    int p = blockIdx.x * 256 + threadIdx.x;
    if (p >= NPTS) return;
    int z = c0[p], y = c1[p], x = c2[p];
    int cell = (z >> 3) * 100 + (y >> 3) * 10 + (x >> 3);
    int pos = atomicAdd(&cellofs[cell], 1);
    perm[pos] = p;                       // sorted -> original index
    pcoord[pos] = z | (y << 8) | (x << 16);
}

// ---------------- K2: conv2, direct-gather A + LDS-shared B (double-buffered) ----------------
// Processes points in cell-sorted order (perm/pcoord); writes g at the ORIGINAL index so
// downstream MLP stays fully coalesced. XCD-chunked block swizzle keeps each XCD's L2 on
// one contiguous spatial slab.
__global__ __launch_bounds__(256) void conv2_mfma(
    const short* __restrict__ f1s, const short* __restrict__ wpb,
    const float* __restrict__ b2,
    const int* __restrict__ perm, const int* __restrict__ pcoord,
    __hip_bfloat16* __restrict__ g)
{
    __shared__ short Blds[2][512 * 8];   // 2 x 8 KB, 16B slots; slot s holds chunk (s&7)^(oc&7) of oc=s>>3

    // bijective XCD-chunked swizzle (m204): works for any grid size
    int bid = blockIdx.x;
    {
        const int nwg = gridDim.x;
        const int qq = nwg >> 3, rr = nwg & 7;
        const int xcd = bid & 7, i = bid >> 3;
        bid = (xcd < rr ? xcd * (qq + 1) : rr * (qq + 1) + (xcd - rr) * qq) + i;
    }

    const int tid = threadIdx.x;
    const int w = tid >> 6, lane = tid & 63;
    const int q = lane >> 4, lc = lane & 15;
    const int pw = bid * 256 + w * 64;    // wave's point base (sorted order)

    int rowbase[4];
    int rowmask[4];
    #pragma unroll
    for (int mt = 0; mt < 4; mt++) {
        int p = pw + mt * 16 + lc;
        if (p > NPTS - 1) p = NPTS - 1;
        int pc = pcoord[p];
        int z = pc & 0xff, y = (pc >> 8) & 0xff, x = (pc >> 16) & 0xff;
        rowbase[mt] = (z * PLANE + y * DD + x) * 64;
        int m = 0;
        #pragma unroll
        for (int off = 0; off < 27; off++) {
            int dz = off / 9, dy = (off / 3) % 3, dx = off % 3;
            int ok = ((unsigned)(z + dz - 1) < DD) & ((unsigned)(y + dy - 1) < DD) &
                     ((unsigned)(x + dx - 1) < DD);
            m |= ok << off;
        }
        rowmask[mt] = m;
    }

    floatx4 acc[4][4];
    #pragma unroll
    for (int mt = 0; mt < 4; mt++)
        #pragma unroll
        for (int nt = 0; nt < 4; nt++)
            acc[mt][nt] = (floatx4){0.f, 0.f, 0.f, 0.f};

    // stage B for offset 0
    #pragma unroll
    for (int it = 0; it < 2; it++) {
        int sb = it * 256 + w * 64;
        int s = sb + lane;
        int oc = s >> 3, cs = (s & 7) ^ (oc & 7);
        async_copy16(&Blds[0][sb * 8], wpb + oc * 1728 + 0 * 64 + cs * 8);
    }
    __syncthreads();

    for (int off = 0; off < 27; ++off) {
        // prefetch B for next offset into the other buffer
        if (off + 1 < 27) {
            #pragma unroll
            for (int it = 0; it < 2; it++) {
                int sb = it * 256 + w * 64;
                int s = sb + lane;
                int oc = s >> 3, cs = (s & 7) ^ (oc & 7);
                async_copy16(&Blds[(off + 1) & 1][sb * 8],
                             wpb + oc * 1728 + (off + 1) * 64 + cs * 8);
            }
        }

        const int dz = off / 9, rem = off - dz * 9;
        const int dy = rem / 3, dx = rem - dy * 3;
        const int delta = ((dz - 1) * PLANE + (dy - 1) * DD + (dx - 1)) * 64;

        // A-frags: 4 mt x 2 ks masked direct gathers (16 B each)
        bf16x8 afr[4][2];
        #pragma unroll
        for (int mt = 0; mt < 4; mt++) {
            const int valid = (rowmask[mt] >> off) & 1;
            #pragma unroll
            for (int ks = 0; ks < 2; ks++) {
                bf16x8 v = (bf16x8)(short)0;
                if (valid)
                    v = *(const bf16x8*)(f1s + rowbase[mt] + delta + ks * 32 + q * 8);
                afr[mt][ks] = v;
            }
        }
        // B-frags from LDS: slot = oc*8 + (kc ^ (oc&7)), oc = nt*16+lc, kc = ks*4+q
        bf16x8 bfr[4][2];
        #pragma unroll
        for (int nt = 0; nt < 4; nt++) {
            const int oc = nt * 16 + lc;
            #pragma unroll
            for (int ks = 0; ks < 2; ks++) {
                const int slot = oc * 8 + ((ks * 4 + q) ^ (oc & 7));
                bfr[nt][ks] = *(const bf16x8*)(&Blds[off & 1][slot * 8]);
            }
        }

        #pragma unroll
        for (int ks = 0; ks < 2; ks++)
            #pragma unroll
            for (int mt = 0; mt < 4; mt++)
                #pragma unroll
                for (int nt = 0; nt < 4; nt++)
                    acc[mt][nt] = __builtin_amdgcn_mfma_f32_16x16x32_bf16(
                        afr[mt][ks], bfr[nt][ks], acc[mt][nt], 0, 0, 0);

        __syncthreads();   // buf[off&1] consumed by all; prefetch for off+1 has landed
    }

    #pragma unroll
    for (int mt = 0; mt < 4; mt++) {
        const int pt = pw + mt * 16 + q * 4;
        int orig[4];
        #pragma unroll
        for (int r = 0; r < 4; r++)
            orig[r] = (pt + r < NPTS) ? perm[pt + r] : -1;
        #pragma unroll
        for (int nt = 0; nt < 4; nt++) {
            const int oc = nt * 16 + lc;
            const float bias = b2[oc];
            #pragma unroll
            for (int r = 0; r < 4; r++) {
                if (orig[r] >= 0) {
                    float v = acc[mt][nt][r] + bias;
                    g[(size_t)orig[r] * 64 + oc] = __float2bfloat16(v > 0.f ? v : 0.f);
                }
            }
        }
    }
}

// ---------------- K3: fused MLP via MFMA. block = 64 points, 4 waves split N ----------------
__global__ __launch_bounds__(256) void mlp_mfma(
    const __hip_bfloat16* __restrict__ g,
    const short* __restrict__ w1b, const float* __restrict__ bp1,
    const short* __restrict__ w2b, const float* __restrict__ bp2,
    const short* __restrict__ w3b, const float* __restrict__ bp3,
    const float* __restrict__ wp4, const float* __restrict__ bp4,
    float* __restrict__ out)
{
    __shared__ short bufA[64 * 256];   // 32 KB: X, then H2
    __shared__ short bufB[64 * 256];   // 32 KB: H1; then fp32 H3 overlay
    float* h3f = (float*)bufB;

    const int tid = threadIdx.x;
    const int pb = blockIdx.x * 64;
    const int w = tid >> 6, lane = tid & 63;
    const int q = lane >> 4, lc = lane & 15;

    const short* gs = (const short*)g;
    #pragma unroll
    for (int it = 0; it < 2; it++) {
        int idx = it * 256 + tid;
        int r = idx >> 3, c = idx & 7;
        int4 v = *(const int4*)(gs + (size_t)(pb + r) * 64 + c * 8);
        *(int4*)(&bufA[r * 256 + (c ^ (r & 7)) * 8]) = v;
    }
    __syncthreads();

    // L1: 64 -> 256, relu
    {
        floatx4 acc[4][4];
        #pragma unroll
        for (int mt = 0; mt < 4; mt++)
            #pragma unroll
            for (int nt = 0; nt < 4; nt++)
                acc[mt][nt] = (floatx4){0.f, 0.f, 0.f, 0.f};

        #pragma unroll
        for (int ks = 0; ks < 2; ks++) {
            bf16x8 bfr[4];
            #pragma unroll
            for (int nt = 0; nt < 4; nt++)
                bfr[nt] = *(const bf16x8*)(w1b + (w * 64 + nt * 16 + lc) * 64 + ks * 32 + q * 8);
            const int c = ks * 4 + q;
            #pragma unroll
            for (int mt = 0; mt < 4; mt++) {
                const int m = mt * 16 + lc;
                bf16x8 afr = *(const bf16x8*)(&bufA[m * 256 + (c ^ (m & 7)) * 8]);
                #pragma unroll
                for (int nt = 0; nt < 4; nt++)
                    acc[mt][nt] = __builtin_amdgcn_mfma_f32_16x16x32_bf16(afr, bfr[nt], acc[mt][nt], 0, 0, 0);
            }
        }
        float bias[4];
        #pragma unroll
        for (int nt = 0; nt < 4; nt++) bias[nt] = bp1[w * 64 + nt * 16 + lc];
        #pragma unroll
        for (int mt = 0; mt < 4; mt++)
            #pragma unroll
            for (int nt = 0; nt < 4; nt++) {
                const int col = w * 64 + nt * 16 + lc;
                #pragma unroll
                for (int r = 0; r < 4; r++) {
                    const int m = mt * 16 + q * 4 + r;
                    float v = acc[mt][nt][r] + bias[nt];
                    v = v > 0.f ? v : 0.f;
                    bufB[m * 256 + (((col >> 3) ^ (m & 7)) * 8 + (col & 7))] = f2bf(v);
                }
            }
    }
    __syncthreads();

    // L2: 256 -> 256, relu
    {
        floatx4 acc[4][4];
        #pragma unroll
        for (int mt = 0; mt < 4; mt++)
            #pragma unroll
            for (int nt = 0; nt < 4; nt++)
                acc[mt][nt] = (floatx4){0.f, 0.f, 0.f, 0.f};

        #pragma unroll
        for (int ks = 0; ks < 8; ks++) {
            bf16x8 bfr[4];
            #pragma unroll
            for (int nt = 0; nt < 4; nt++)
                bfr[nt] = *(const bf16x8*)(w2b + (w * 64 + nt * 16 + lc) * 256 + ks * 32 + q * 8);
            const int c = ks * 4 + q;
            #pragma unroll
            for (int mt = 0; mt < 4; mt++) {
                const int m = mt * 16 + lc;
                const int pc = (c & 24) | ((c & 7) ^ (m & 7));
                bf16x8 afr = *(const bf16x8*)(&bufB[m * 256 + pc * 8]);
                #pragma unroll
                for (int nt = 0; nt < 4; nt++)
                    acc[mt][nt] = __builtin_amdgcn_mfma_f32_16x16x32_bf16(afr, bfr[nt], acc[mt][nt], 0, 0, 0);
            }
        }
        float bias[4];
        #pragma unroll
        for (int nt = 0; nt < 4; nt++) bias[nt] = bp2[w * 64 + nt * 16 + lc];
        __syncthreads();
        #pragma unroll
        for (int mt = 0; mt < 4; mt++)
            #pragma unroll
            for (int nt = 0; nt < 4; nt++) {
                const int col = w * 64 + nt * 16 + lc;
                #pragma unroll
                for (int r = 0; r < 4; r++) {
                    const int m = mt * 16 + q * 4 + r;
                    float v = acc[mt][nt][r] + bias[nt];
                    v = v > 0.f ? v : 0.f;
                    bufA[m * 256 + (((col >> 3) ^ (m & 7)) * 8 + (col & 7))] = f2bf(v);
                }
            }
    }
    __syncthreads();

    // L3: 256 -> 64
    {
        floatx4 acc[4];
        #pragma unroll
        for (int mt = 0; mt < 4; mt++) acc[mt] = (floatx4){0.f, 0.f, 0.f, 0.f};

        #pragma unroll
        for (int ks = 0; ks < 8; ks++) {
            bf16x8 bfr = *(const bf16x8*)(w3b + (w * 16 + lc) * 256 + ks * 32 + q * 8);
            const int c = ks * 4 + q;
            #pragma unroll
            for (int mt = 0; mt < 4; mt++) {
                const int m = mt * 16 + lc;
                const int pc = (c & 24) | ((c & 7) ^ (m & 7));
                bf16x8 afr = *(const bf16x8*)(&bufA[m * 256 + pc * 8]);
                acc[mt] = __builtin_amdgcn_mfma_f32_16x16x32_bf16(afr, bfr, acc[mt], 0, 0, 0);
            }
        }
        const float bias = bp3[w * 16 + lc];
        const int col = w * 16 + lc;
        __syncthreads();
        #pragma unroll
        for (int mt = 0; mt < 4; mt++)
            #pragma unroll
            for (int r = 0; r < 4; r++) {
                const int m = mt * 16 + q * 4 + r;
                h3f[m * 65 + col] = acc[mt][r] + bias;
            }
    }
    __syncthreads();

    // L4: 64 -> 6
    for (int e = tid; e < 384; e += 256) {
        int c = e >> 6, p = e & 63;
        float a = bp4[c];
        const float* wr = wp4 + c * 64;
        const float* xr = h3f + p * 65;
        #pragma unroll 8
        for (int k = 0; k < 64; k++) a += wr[k] * xr[k];
        out[(size_t)c * NPTS + pb + p] = a;
    }
}

extern "C" void kernel_launch(void* const* d_in, const int* in_sizes, int n_in,
                              void* d_out, int out_size, void* d_ws, size_t ws_size,
                              hipStream_t stream) {
    const float* img = (const float*)d_in[0];
    const int* c0 = (const int*)d_in[1];
    const int* c1 = (const int*)d_in[2];
    const int* c2 = (const int*)d_in[3];
    const float* w_enc1 = (const float*)d_in[4];
    const float* b_enc1 = (const float*)d_in[5];
    const float* w_enc2 = (const float*)d_in[6];
    const float* b_enc2 = (const float*)d_in[7];
    const float* w_p1 = (const float*)d_in[8];
    const float* b_p1 = (const float*)d_in[9];
    const float* w_p2 = (const float*)d_in[10];
    const float* b_p2 = (const float*)d_in[11];
    const float* w_p3 = (const float*)d_in[12];
    const float* b_p3 = (const float*)d_in[13];
    const float* w_p4 = (const float*)d_in[14];
    const float* b_p4 = (const float*)d_in[15];
    float* out = (float*)d_out;

    short* f1b = (short*)d_ws;                       // 32,768,000
    short* wpb = f1b + (size_t)VOX * 64;             // 110592
    short* w1b = wpb + 110592;                       // 16384
    short* w2b = w1b + 16384;                        // 65536
    short* w3b = w2b + 65536;                        // 16384
    short* gb  = w3b + 16384;                        // 12,800,000
    short* img_t = gb + (size_t)NPTS * 64;           // 16,384,000
    short* wc1 = img_t + (size_t)VOX * 32;           // 55296
    short* zeros = wc1 + 55296;                      // 32 shorts (64 B zero source)

    // binning arrays alias img_t (free after conv1 consumes it)
    int* perm   = (int*)img_t;                       // 200000 ints
    int* pcoord = perm + NPTS;                       // 200000 ints
    int* hist   = pcoord + NPTS;                     // 1000 ints

    hipMemsetAsync(zeros, 0, 64, stream);
    convert_weights<<<(264192 + 255) / 256, 256, 0, stream>>>(
        w_enc2, w_p1, w_p2, w_p3, w_enc1, wpb, w1b, w2b, w3b, wc1);
    transpose_img<<<(VOX + 255) / 256, 256, 0, stream>>>(img, img_t);
    conv1_mfma<<<DD * DD, 256, 0, stream>>>(img_t, wc1, b_enc1, zeros, f1b);

    // counting sort of points into 8^3 cells (img_t region is free now)
    hipMemsetAsync(hist, 0, 1000 * sizeof(int), stream);
    hist_cells<<<(NPTS + 255) / 256, 256, 0, stream>>>(c0, c1, c2, hist);
    scan_cells<<<1, 1024, 0, stream>>>(hist);
    scatter_points<<<(NPTS + 255) / 256, 256, 0, stream>>>(c0, c1, c2, hist, perm, pcoord);

    conv2_mfma<<<(NPTS + 255) / 256, 256, 0, stream>>>(
        f1b, wpb, b_enc2, perm, pcoord, (__hip_bfloat16*)gb);
    mlp_mfma<<<NPTS / 64, 256, 0, stream>>>(
        (const __hip_bfloat16*)gb, w1b, b_p1, w2b, b_p2, w3b, b_p3, w_p4, b_p4, out);
}

// Round 2
// 535.482 us; speedup vs baseline: 1.0003x; 1.0003x over previous
//
#include <hip/hip_runtime.h>
#include <hip/hip_bf16.h>

#define DD 80
#define CIN 32
#define PLANE (DD*DD)        // 6400
#define VOX (DD*DD*DD)       // 512000
#define NPTS 200000

typedef __attribute__((ext_vector_type(8))) short bf16x8;
typedef __attribute__((ext_vector_type(4))) float floatx4;

static __device__ __forceinline__ short f2bf(float v) {
    __hip_bfloat16 b = __float2bfloat16(v);
    return *(short*)&b;
}

// async global->LDS 16B copy: lane's 16B lands at ldsbase + lane*16 (wave-uniform base)
static __device__ __forceinline__ void async_copy16(void* lds, const void* g) {
    __builtin_amdgcn_global_load_lds(
        (const __attribute__((address_space(1))) unsigned int*)g,
        (__attribute__((address_space(3))) unsigned int*)lds, 16, 0, 0);
}

// ---------------- K0: convert/permute all weights to bf16 ----------------
// wpb layout: [off][oc][ic]  (off*4096 + oc*64 + ic) -- each offset's 8 KB contiguous
__global__ void convert_weights(const float* __restrict__ w2,
                                const float* __restrict__ w_p1,
                                const float* __restrict__ w_p2,
                                const float* __restrict__ w_p3,
                                const float* __restrict__ w_e1,
                                short* __restrict__ wpb, short* __restrict__ w1b,
                                short* __restrict__ w2b, short* __restrict__ w3b,
                                short* __restrict__ wc1) {
    int i = blockIdx.x * 256 + threadIdx.x;      // total 264192
    if (i < 110592) {
        int off = i >> 12, r = i & 4095;
        int oc = r >> 6, ic = r & 63;
        wpb[i] = f2bf(w2[oc * 1728 + ic * 27 + off]);
    } else if (i < 110592 + 16384) {
        int j = i - 110592;
        w1b[j] = f2bf(w_p1[j]);
    } else if (i < 110592 + 16384 + 65536) {
        int j = i - 110592 - 16384;
        w2b[j] = f2bf(w_p2[j]);
    } else if (i < 110592 + 16384 + 65536 + 16384) {
        int j = i - 110592 - 16384 - 65536;
        w3b[j] = f2bf(w_p3[j]);
    } else if (i < 110592 + 16384 + 65536 + 16384 + 55296) {
        int j = i - (110592 + 16384 + 65536 + 16384);   // [off][oc][ic]
        int off = j / 2048, r = j - off * 2048;
        int oc = r >> 5, ic = r & 31;
        wc1[j] = f2bf(w_e1[(oc * 32 + ic) * 27 + off]);
    }
}

// ---------------- K0b: transpose img (32,VOX) fp32 -> img_t [vox][32] bf16 ----------------
__global__ __launch_bounds__(256) void transpose_img(
    const float* __restrict__ img, short* __restrict__ img_t)
{
    int v = blockIdx.x * 256 + threadIdx.x;
    if (v >= VOX) return;
    short row[32];
    #pragma unroll
    for (int ic = 0; ic < 32; ic++)
        row[ic] = f2bf(img[(size_t)ic * VOX + v]);
    int4* dst = (int4*)(img_t + (size_t)v * 32);
    #pragma unroll
    for (int c = 0; c < 4; c++) dst[c] = ((int4*)row)[c];
}

// ---------------- K1: conv1 via implicit-GEMM MFMA, async LDS staging ----------------
__global__ __launch_bounds__(256) void conv1_mfma(
    const short* __restrict__ img_t, const short* __restrict__ wc1,
    const float* __restrict__ b1, const short* __restrict__ zeros,
    short* __restrict__ f1)
{
    __shared__ short Alds[3072 * 16 / 2];   // 48 KB

    const int bh = blockIdx.x;
    const int d = bh / DD, h = bh - d * DD;
    const int tid = threadIdx.x;
    const int w = tid >> 6, lane = tid & 63;
    const int q = lane >> 4, lc = lane & 15;

    for (int i = 0; i < 12; i++) {
        int s = (w * 12 + i) * 64 + lane;      // slot 0..3071
        int row = s >> 2, c = s & 3;
        int cs = c ^ (row & 3);                // swizzled source chunk
        int rr = row / 82, v = row - rr * 82;
        int dz = rr / 3, dyy = rr - dz * 3;
        int zz = d + dz - 1, yy = h + dyy - 1, ww = v - 1;
        const short* src = zeros;
        if (row < 738 && (unsigned)zz < DD && (unsigned)yy < DD && (unsigned)ww < DD)
            src = img_t + ((size_t)(zz * PLANE + yy * DD + ww)) * 32 + cs * 8;
        async_copy16(&Alds[(w * 12 + i) * 512], src);
    }
    __syncthreads();

    floatx4 acc[5];
    #pragma unroll
    for (int mt = 0; mt < 5; mt++) acc[mt] = (floatx4){0.f, 0.f, 0.f, 0.f};

    #pragma unroll 3
    for (int off = 0; off < 27; ++off) {
        const int dz = off / 9, rem = off - dz * 9;
        const int dy = rem / 3, dx = rem - dy * 3;
        const int rr = dz * 3 + dy;
        bf16x8 bfr = *(const bf16x8*)(wc1 + ((off * 64 + w * 16 + lc) << 5) + q * 8);
        #pragma unroll
        for (int mt = 0; mt < 5; mt++) {
            const int vv = rr * 82 + mt * 16 + lc + dx;
            bf16x8 afr = *(const bf16x8*)(&Alds[vv * 32 + ((q ^ (vv & 3)) << 3)]);
            acc[mt] = __builtin_amdgcn_mfma_f32_16x16x32_bf16(afr, bfr, acc[mt], 0, 0, 0);
        }
    }

    const int oc = w * 16 + lc;
    const float bias = b1[oc];
    const size_t vbase = (size_t)(d * DD + h) * DD;
    #pragma unroll
    for (int mt = 0; mt < 5; mt++) {
        #pragma unroll
        for (int r = 0; r < 4; r++) {
            const int m = mt * 16 + q * 4 + r;
            float v = acc[mt][r] + bias;
            f1[(vbase + m) * 64 + oc] = f2bf(v > 0.f ? v : 0.f);
        }
    }
}

// ---------------- K2: conv2 -- barrier-free, no LDS ----------------
// B read directly from global (8 KB/offset, L1/L2-resident, shared by all waves on the CU).
// A gathered to registers with an explicit 2-deep prefetch pipeline (offset k+1's gathers
// issue before offset k's MFMAs). No __syncthreads anywhere -> waves slip freely and the
// CU scheduler hides gather latency across all resident waves.
__global__ __launch_bounds__(256) void conv2_mfma(
    const short* __restrict__ f1s, const short* __restrict__ wpb,
    const float* __restrict__ b2,
    const int* __restrict__ c0, const int* __restrict__ c1, const int* __restrict__ c2,
    const short* __restrict__ zeros,
    __hip_bfloat16* __restrict__ g)
{
    const int tid = threadIdx.x;
    const int w = tid >> 6, lane = tid & 63;
    const int q = lane >> 4, lc = lane & 15;
    const int pw = blockIdx.x * 256 + w * 64;    // wave's point base

    const short* arow[4];
    int rowmask[4];
    #pragma unroll
    for (int mt = 0; mt < 4; mt++) {
        int p = pw + mt * 16 + lc;
        if (p > NPTS - 1) p = NPTS - 1;
        int z = c0[p], y = c1[p], x = c2[p];
        arow[mt] = f1s + (size_t)(z * PLANE + y * DD + x) * 64;
        int m = 0;
        #pragma unroll
        for (int off = 0; off < 27; off++) {
            int dz = off / 9, dy = (off / 3) % 3, dx = off % 3;
            int ok = ((unsigned)(z + dz - 1) < DD) & ((unsigned)(y + dy - 1) < DD) &
                     ((unsigned)(x + dx - 1) < DD);
            m |= ok << off;
        }
        rowmask[mt] = m;
    }

    floatx4 acc[4][4];
    #pragma unroll
    for (int mt = 0; mt < 4; mt++)
        #pragma unroll
        for (int nt = 0; nt < 4; nt++)
            acc[mt][nt] = (floatx4){0.f, 0.f, 0.f, 0.f};

    const short* zrs = zeros;

#define LOAD_A(off, dst)                                                      \
    {                                                                         \
        const int dz_ = (off) / 9, rem_ = (off) - dz_ * 9;                    \
        const int dy_ = rem_ / 3, dx_ = rem_ - dy_ * 3;                       \
        const int delta_ = ((dz_ - 1) * PLANE + (dy_ - 1) * DD + (dx_ - 1)) * 64; \
        _Pragma("unroll")                                                     \
        for (int mt = 0; mt < 4; mt++) {                                      \
            const short* src_ = ((rowmask[mt] >> (off)) & 1)                  \
                                    ? arow[mt] + delta_ : zrs;                \
            dst[mt][0] = *(const bf16x8*)(src_ + q * 8);                      \
            dst[mt][1] = *(const bf16x8*)(src_ + 32 + q * 8);                 \
        }                                                                     \
    }

#define DO_OFF(off, abuf)                                                     \
    {                                                                         \
        bf16x8 bfr[4][2];                                                     \
        _Pragma("unroll")                                                     \
        for (int nt = 0; nt < 4; nt++) {                                      \
            const int oc_ = nt * 16 + lc;                                     \
            _Pragma("unroll")                                                 \
            for (int ks = 0; ks < 2; ks++)                                    \
                bfr[nt][ks] = *(const bf16x8*)(wpb + ((off) << 12) +          \
                                               oc_ * 64 + (ks * 4 + q) * 8);  \
        }                                                                     \
        _Pragma("unroll")                                                     \
        for (int ks = 0; ks < 2; ks++)                                        \
            _Pragma("unroll")                                                 \
            for (int mt = 0; mt < 4; mt++)                                    \
                _Pragma("unroll")                                             \
                for (int nt = 0; nt < 4; nt++)                                \
                    acc[mt][nt] = __builtin_amdgcn_mfma_f32_16x16x32_bf16(    \
                        abuf[mt][ks], bfr[nt][ks], acc[mt][nt], 0, 0, 0);     \
    }

    bf16x8 A0[4][2], A1[4][2];
    LOAD_A(0, A0)
    #pragma unroll
    for (int base = 0; base < 26; base += 2) {
        LOAD_A(base + 1, A1)
        DO_OFF(base, A0)
        LOAD_A(base + 2, A0)
        DO_OFF(base + 1, A1)
    }
    DO_OFF(26, A0)

#undef LOAD_A
#undef DO_OFF

    #pragma unroll
    for (int nt = 0; nt < 4; nt++) {
        const int oc = nt * 16 + lc;
        const float bias = b2[oc];
        #pragma unroll
        for (int mt = 0; mt < 4; mt++) {
            const int pt = pw + mt * 16 + q * 4;
            #pragma unroll
            for (int r = 0; r < 4; r++) {
                if (pt + r < NPTS) {
                    float v = acc[mt][nt][r] + bias;
                    g[(size_t)(pt + r) * 64 + oc] = __float2bfloat16(v > 0.f ? v : 0.f);
                }
            }
        }
    }
}

// ---------------- K3: fused MLP via MFMA. block = 64 points, 4 waves split N ----------------
__global__ __launch_bounds__(256) void mlp_mfma(
    const __hip_bfloat16* __restrict__ g,
    const short* __restrict__ w1b, const float* __restrict__ bp1,
    const short* __restrict__ w2b, const float* __restrict__ bp2,
    const short* __restrict__ w3b, const float* __restrict__ bp3,
    const float* __restrict__ wp4, const float* __restrict__ bp4,
    float* __restrict__ out)
{
    __shared__ short bufA[64 * 256];   // 32 KB: X, then H2
    __shared__ short bufB[64 * 256];   // 32 KB: H1; then fp32 H3 overlay
    float* h3f = (float*)bufB;

    const int tid = threadIdx.x;
    const int pb = blockIdx.x * 64;
    const int w = tid >> 6, lane = tid & 63;
    const int q = lane >> 4, lc = lane & 15;

    const short* gs = (const short*)g;
    #pragma unroll
    for (int it = 0; it < 2; it++) {
        int idx = it * 256 + tid;
        int r = idx >> 3, c = idx & 7;
        int4 v = *(const int4*)(gs + (size_t)(pb + r) * 64 + c * 8);
        *(int4*)(&bufA[r * 256 + (c ^ (r & 7)) * 8]) = v;
    }
    __syncthreads();

    // L1: 64 -> 256, relu
    {
        floatx4 acc[4][4];
        #pragma unroll
        for (int mt = 0; mt < 4; mt++)
            #pragma unroll
            for (int nt = 0; nt < 4; nt++)
                acc[mt][nt] = (floatx4){0.f, 0.f, 0.f, 0.f};

        #pragma unroll
        for (int ks = 0; ks < 2; ks++) {
            bf16x8 bfr[4];
            #pragma unroll
            for (int nt = 0; nt < 4; nt++)
                bfr[nt] = *(const bf16x8*)(w1b + (w * 64 + nt * 16 + lc) * 64 + ks * 32 + q * 8);
            const int c = ks * 4 + q;
            #pragma unroll
            for (int mt = 0; mt < 4; mt++) {
                const int m = mt * 16 + lc;
                bf16x8 afr = *(const bf16x8*)(&bufA[m * 256 + (c ^ (m & 7)) * 8]);
                #pragma unroll
                for (int nt = 0; nt < 4; nt++)
                    acc[mt][nt] = __builtin_amdgcn_mfma_f32_16x16x32_bf16(afr, bfr[nt], acc[mt][nt], 0, 0, 0);
            }
        }
        float bias[4];
        #pragma unroll
        for (int nt = 0; nt < 4; nt++) bias[nt] = bp1[w * 64 + nt * 16 + lc];
        #pragma unroll
        for (int mt = 0; mt < 4; mt++)
            #pragma unroll
            for (int nt = 0; nt < 4; nt++) {
                const int col = w * 64 + nt * 16 + lc;
                #pragma unroll
                for (int r = 0; r < 4; r++) {
                    const int m = mt * 16 + q * 4 + r;
                    float v = acc[mt][nt][r] + bias[nt];
                    v = v > 0.f ? v : 0.f;
                    bufB[m * 256 + (((col >> 3) ^ (m & 7)) * 8 + (col & 7))] = f2bf(v);
                }
            }
    }
    __syncthreads();

    // L2: 256 -> 256, relu
    {
        floatx4 acc[4][4];
        #pragma unroll
        for (int mt = 0; mt < 4; mt++)
            #pragma unroll
            for (int nt = 0; nt < 4; nt++)
                acc[mt][nt] = (floatx4){0.f, 0.f, 0.f, 0.f};

        #pragma unroll
        for (int ks = 0; ks < 8; ks++) {
            bf16x8 bfr[4];
            #pragma unroll
            for (int nt = 0; nt < 4; nt++)
                bfr[nt] = *(const bf16x8*)(w2b + (w * 64 + nt * 16 + lc) * 256 + ks * 32 + q * 8);
            const int c = ks * 4 + q;
            #pragma unroll
            for (int mt = 0; mt < 4; mt++) {
                const int m = mt * 16 + lc;
                const int pc = (c & 24) | ((c & 7) ^ (m & 7));
                bf16x8 afr = *(const bf16x8*)(&bufB[m * 256 + pc * 8]);
                #pragma unroll
                for (int nt = 0; nt < 4; nt++)
                    acc[mt][nt] = __builtin_amdgcn_mfma_f32_16x16x32_bf16(afr, bfr[nt], acc[mt][nt], 0, 0, 0);
            }
        }
        float bias[4];
        #pragma unroll
        for (int nt = 0; nt < 4; nt++) bias[nt] = bp2[w * 64 + nt * 16 + lc];
        __syncthreads();
        #pragma unroll
        for (int mt = 0; mt < 4; mt++)
            #pragma unroll
            for (int nt = 0; nt < 4; nt++) {
                const int col = w * 64 + nt * 16 + lc;
                #pragma unroll
                for (int r = 0; r < 4; r++) {
                    const int m = mt * 16 + q * 4 + r;
                    float v = acc[mt][nt][r] + bias[nt];
                    v = v > 0.f ? v : 0.f;
                    bufA[m * 256 + (((col >> 3) ^ (m & 7)) * 8 + (col & 7))] = f2bf(v);
                }
            }
    }
    __syncthreads();

    // L3: 256 -> 64
    {
        floatx4 acc[4];
        #pragma unroll
        for (int mt = 0; mt < 4; mt++) acc[mt] = (floatx4){0.f, 0.f, 0.f, 0.f};

        #pragma unroll
        for (int ks = 0; ks < 8; ks++) {
            bf16x8 bfr = *(const bf16x8*)(w3b + (w * 16 + lc) * 256 + ks * 32 + q * 8);
            const int c = ks * 4 + q;
            #pragma unroll
            for (int mt = 0; mt < 4; mt++) {
                const int m = mt * 16 + lc;
                const int pc = (c & 24) | ((c & 7) ^ (m & 7));
                bf16x8 afr = *(const bf16x8*)(&bufA[m * 256 + pc * 8]);
                acc[mt] = __builtin_amdgcn_mfma_f32_16x16x32_bf16(afr, bfr, acc[mt], 0, 0, 0);
            }
        }
        const float bias = bp3[w * 16 + lc];
        const int col = w * 16 + lc;
        __syncthreads();
        #pragma unroll
        for (int mt = 0; mt < 4; mt++)
            #pragma unroll
            for (int r = 0; r < 4; r++) {
                const int m = mt * 16 + q * 4 + r;
                h3f[m * 65 + col] = acc[mt][r] + bias;
            }
    }
    __syncthreads();

    // L4: 64 -> 6
    for (int e = tid; e < 384; e += 256) {
        int c = e >> 6, p = e & 63;
        float a = bp4[c];
        const float* wr = wp4 + c * 64;
        const float* xr = h3f + p * 65;
        #pragma unroll 8
        for (int k = 0; k < 64; k++) a += wr[k] * xr[k];
        out[(size_t)c * NPTS + pb + p] = a;
    }
}

extern "C" void kernel_launch(void* const* d_in, const int* in_sizes, int n_in,
                              void* d_out, int out_size, void* d_ws, size_t ws_size,
                              hipStream_t stream) {
    const float* img = (const float*)d_in[0];
    const int* c0 = (const int*)d_in[1];
    const int* c1 = (const int*)d_in[2];
    const int* c2 = (const int*)d_in[3];
    const float* w_enc1 = (const float*)d_in[4];
    const float* b_enc1 = (const float*)d_in[5];
    const float* w_enc2 = (const float*)d_in[6];
    const float* b_enc2 = (const float*)d_in[7];
    const float* w_p1 = (const float*)d_in[8];
    const float* b_p1 = (const float*)d_in[9];
    const float* w_p2 = (const float*)d_in[10];
    const float* b_p2 = (const float*)d_in[11];
    const float* w_p3 = (const float*)d_in[12];
    const float* b_p3 = (const float*)d_in[13];
    const float* w_p4 = (const float*)d_in[14];
    const float* b_p4 = (const float*)d_in[15];
    float* out = (float*)d_out;

    short* f1b = (short*)d_ws;                       // 32,768,000
    short* wpb = f1b + (size_t)VOX * 64;             // 110592
    short* w1b = wpb + 110592;                       // 16384
    short* w2b = w1b + 16384;                        // 65536
    short* w3b = w2b + 65536;                        // 16384
    short* gb  = w3b + 16384;                        // 12,800,000
    short* img_t = gb + (size_t)NPTS * 64;           // 16,384,000
    short* wc1 = img_t + (size_t)VOX * 32;           // 55296
    short* zeros = wc1 + 55296;                      // 64 shorts (128 B zero source)

    hipMemsetAsync(zeros, 0, 128, stream);
    convert_weights<<<(264192 + 255) / 256, 256, 0, stream>>>(
        w_enc2, w_p1, w_p2, w_p3, w_enc1, wpb, w1b, w2b, w3b, wc1);
    transpose_img<<<(VOX + 255) / 256, 256, 0, stream>>>(img, img_t);
    conv1_mfma<<<DD * DD, 256, 0, stream>>>(img_t, wc1, b_enc1, zeros, f1b);
    conv2_mfma<<<(NPTS + 255) / 256, 256, 0, stream>>>(
        f1b, wpb, b_enc2, c0, c1, c2, zeros, (__hip_bfloat16*)gb);
    mlp_mfma<<<NPTS / 64, 256, 0, stream>>>(
        (const __hip_bfloat16*)gb, w1b, b_p1, w2b, b_p2, w3b, b_p3, w_p4, b_p4, out);
}

// Round 3
// 436.293 us; speedup vs baseline: 1.2277x; 1.2273x over previous
//
#include <hip/hip_runtime.h>
#include <hip/hip_bf16.h>

#define DD 80
#define CIN 32
#define PLANE (DD*DD)        // 6400
#define VOX (DD*DD*DD)       // 512000
#define NPTS 200000

typedef __attribute__((ext_vector_type(8))) short bf16x8;
typedef __attribute__((ext_vector_type(4))) float floatx4;

static __device__ __forceinline__ short f2bf(float v) {
    __hip_bfloat16 b = __float2bfloat16(v);
    return *(short*)&b;
}

// async global->LDS 16B copy: lane's 16B lands at ldsbase + lane*16 (wave-uniform base);
// the GLOBAL source address is per-lane.
static __device__ __forceinline__ void async_copy16(void* lds, const void* g) {
    __builtin_amdgcn_global_load_lds(
        (const __attribute__((address_space(1))) unsigned int*)g,
        (__attribute__((address_space(3))) unsigned int*)lds, 16, 0, 0);
}

// ---------------- K0: convert/permute all weights to bf16 ----------------
// wpb layout: [oc][off][ic]  (oc*1728 + off*64 + ic)  -- round-0 layout for LDS B staging
__global__ void convert_weights(const float* __restrict__ w2,
                                const float* __restrict__ w_p1,
                                const float* __restrict__ w_p2,
                                const float* __restrict__ w_p3,
                                const float* __restrict__ w_e1,
                                short* __restrict__ wpb, short* __restrict__ w1b,
                                short* __restrict__ w2b, short* __restrict__ w3b,
                                short* __restrict__ wc1) {
    int i = blockIdx.x * 256 + threadIdx.x;      // total 264192
    if (i < 110592) {
        int oc = i / 1728, j = i - oc * 1728;
        int off = j >> 6, ic = j & 63;
        wpb[i] = f2bf(w2[oc * 1728 + ic * 27 + off]);
    } else if (i < 110592 + 16384) {
        int j = i - 110592;
        w1b[j] = f2bf(w_p1[j]);
    } else if (i < 110592 + 16384 + 65536) {
        int j = i - 110592 - 16384;
        w2b[j] = f2bf(w_p2[j]);
    } else if (i < 110592 + 16384 + 65536 + 16384) {
        int j = i - 110592 - 16384 - 65536;
        w3b[j] = f2bf(w_p3[j]);
    } else if (i < 110592 + 16384 + 65536 + 16384 + 55296) {
        int j = i - (110592 + 16384 + 65536 + 16384);   // [off][oc][ic]
        int off = j / 2048, r = j - off * 2048;
        int oc = r >> 5, ic = r & 31;
        wc1[j] = f2bf(w_e1[(oc * 32 + ic) * 27 + off]);
    }
}

// ---------------- K0b: transpose img (32,VOX) fp32 -> img_t [vox][32] bf16 ----------------
__global__ __launch_bounds__(256) void transpose_img(
    const float* __restrict__ img, short* __restrict__ img_t)
{
    int v = blockIdx.x * 256 + threadIdx.x;
    if (v >= VOX) return;
    short row[32];
    #pragma unroll
    for (int ic = 0; ic < 32; ic++)
        row[ic] = f2bf(img[(size_t)ic * VOX + v]);
    int4* dst = (int4*)(img_t + (size_t)v * 32);
    #pragma unroll
    for (int c = 0; c < 4; c++) dst[c] = ((int4*)row)[c];
}

// ---------------- K1: conv1 via implicit-GEMM MFMA, async LDS staging ----------------
__global__ __launch_bounds__(256) void conv1_mfma(
    const short* __restrict__ img_t, const short* __restrict__ wc1,
    const float* __restrict__ b1, const short* __restrict__ zeros,
    short* __restrict__ f1)
{
    __shared__ short Alds[3072 * 16 / 2];   // 48 KB

    const int bh = blockIdx.x;
    const int d = bh / DD, h = bh - d * DD;
    const int tid = threadIdx.x;
    const int w = tid >> 6, lane = tid & 63;
    const int q = lane >> 4, lc = lane & 15;

    for (int i = 0; i < 12; i++) {
        int s = (w * 12 + i) * 64 + lane;      // slot 0..3071
        int row = s >> 2, c = s & 3;
        int cs = c ^ (row & 3);                // swizzled source chunk
        int rr = row / 82, v = row - rr * 82;
        int dz = rr / 3, dyy = rr - dz * 3;
        int zz = d + dz - 1, yy = h + dyy - 1, ww = v - 1;
        const short* src = zeros;
        if (row < 738 && (unsigned)zz < DD && (unsigned)yy < DD && (unsigned)ww < DD)
            src = img_t + ((size_t)(zz * PLANE + yy * DD + ww)) * 32 + cs * 8;
        async_copy16(&Alds[(w * 12 + i) * 512], src);
    }
    __syncthreads();

    floatx4 acc[5];
    #pragma unroll
    for (int mt = 0; mt < 5; mt++) acc[mt] = (floatx4){0.f, 0.f, 0.f, 0.f};

    #pragma unroll 3
    for (int off = 0; off < 27; ++off) {
        const int dz = off / 9, rem = off - dz * 9;
        const int dy = rem / 3, dx = rem - dy * 3;
        const int rr = dz * 3 + dy;
        bf16x8 bfr = *(const bf16x8*)(wc1 + ((off * 64 + w * 16 + lc) << 5) + q * 8);
        #pragma unroll
        for (int mt = 0; mt < 5; mt++) {
            const int vv = rr * 82 + mt * 16 + lc + dx;
            bf16x8 afr = *(const bf16x8*)(&Alds[vv * 32 + ((q ^ (vv & 3)) << 3)]);
            acc[mt] = __builtin_amdgcn_mfma_f32_16x16x32_bf16(afr, bfr, acc[mt], 0, 0, 0);
        }
    }

    const int oc = w * 16 + lc;
    const float bias = b1[oc];
    const size_t vbase = (size_t)(d * DD + h) * DD;
    #pragma unroll
    for (int mt = 0; mt < 5; mt++) {
        #pragma unroll
        for (int r = 0; r < 4; r++) {
            const int m = mt * 16 + q * 4 + r;
            float v = acc[mt][r] + bias;
            f1[(vbase + m) * 64 + oc] = f2bf(v > 0.f ? v : 0.f);
        }
    }
}

// ---------------- K2: conv2 -- full-line A gather via global_load_lds ----------------
// Round-0 structure (LDS-staged B, double-buffered, barrier per offset) with the A-path
// rebuilt: each point's 128 B row is fetched by 8 ADJACENT lanes as one full-line,
// fully-coalesced transaction, landing directly in a per-wave LDS tile (no VGPR trip).
// Chunk permutation for conflict-reduced MFMA-fragment reads is applied by pre-swizzling
// the per-lane GLOBAL source address (LDS dest of global_load_lds must stay linear).
__global__ __launch_bounds__(256) void conv2_mfma(
    const short* __restrict__ f1s, const short* __restrict__ wpb,
    const float* __restrict__ b2,
    const int* __restrict__ c0, const int* __restrict__ c1, const int* __restrict__ c2,
    const short* __restrict__ zeros,
    __hip_bfloat16* __restrict__ g)
{
    __shared__ short Blds[2][512 * 8];   // 16 KB: slot s holds chunk (s&7)^(oc&7) of oc=s>>3
    __shared__ short Alds[4][64 * 64];   // 32 KB: per-wave [64 rows][8 slots x 8 shorts]

    const int tid = threadIdx.x;
    const int w = tid >> 6, lane = tid & 63;
    const int q = lane >> 4, lc = lane & 15;
    const int pw = blockIdx.x * 256 + w * 64;    // wave's point base

    // staging-lane mapping: instr i covers rows 8i..8i+7; this lane owns row 8i+pr,
    // slot pc, whose content is source chunk cc = pc ^ pr (slot s of row r holds chunk s^(r&7))
    const int pr = lane >> 3;           // 0..7
    const int pc = lane & 7;            // slot within row
    const int cc = pc ^ pr;             // source chunk (16B units)

    const short* srow[8];
    int smask[8];
    #pragma unroll
    for (int i = 0; i < 8; i++) {
        int p = pw + 8 * i + pr;
        if (p > NPTS - 1) p = NPTS - 1;
        int z = c0[p], y = c1[p], x = c2[p];
        srow[i] = f1s + (size_t)(z * PLANE + y * DD + x) * 64 + cc * 8;
        int m = 0;
        #pragma unroll
        for (int off = 0; off < 27; off++) {
            int dz = off / 9, dy = (off / 3) % 3, dx = off % 3;
            int ok = ((unsigned)(z + dz - 1) < DD) & ((unsigned)(y + dy - 1) < DD) &
                     ((unsigned)(x + dx - 1) < DD);
            m |= ok << off;
        }
        smask[i] = m;
    }
    const short* zsrc = zeros + cc * 8;   // zeros page is 128 B

    floatx4 acc[4][4];
    #pragma unroll
    for (int mt = 0; mt < 4; mt++)
        #pragma unroll
        for (int nt = 0; nt < 4; nt++)
            acc[mt][nt] = (floatx4){0.f, 0.f, 0.f, 0.f};

    // stage B for offset 0
    #pragma unroll
    for (int it = 0; it < 2; it++) {
        int sb = it * 256 + w * 64;
        int s = sb + lane;
        int oc = s >> 3, cs = (s & 7) ^ (oc & 7);
        async_copy16(&Blds[0][sb * 8], wpb + oc * 1728 + 0 * 64 + cs * 8);
    }
    __syncthreads();

    for (int off = 0; off < 27; ++off) {
        const int dz = off / 9, rem = off - dz * 9;
        const int dy = rem / 3, dx = rem - dy * 3;
        const int delta = ((dz - 1) * PLANE + (dy - 1) * DD + (dx - 1)) * 64;

        // stage A(off): 8 instr x 1 KB, each = 8 full 128B lines, adjacent-lane coalesced
        #pragma unroll
        for (int i = 0; i < 8; i++) {
            const short* src = ((smask[i] >> off) & 1) ? srow[i] + delta : zsrc;
            async_copy16(&Alds[w][i * 512], src);
        }
        // prefetch B(off+1) into other buffer (issue AFTER A so vmcnt(2) leaves only B in flight;
        // wrap at the last offset keeps the count uniform -- that copy is never read)
        {
            const int noff = (off + 1 < 27) ? off + 1 : 0;
            #pragma unroll
            for (int it = 0; it < 2; it++) {
                int sb = it * 256 + w * 64;
                int s = sb + lane;
                int oc = s >> 3, cs = (s & 7) ^ (oc & 7);
                async_copy16(&Blds[(off + 1) & 1][sb * 8],
                             wpb + oc * 1728 + noff * 64 + cs * 8);
            }
        }
        asm volatile("s_waitcnt vmcnt(2)" ::: "memory");   // A landed; B(off+1) still in flight

        // A frags from per-wave LDS: row = mt*16+lc, chunk = ks*4+q at slot chunk^(row&7)
        bf16x8 afr[4][2];
        #pragma unroll
        for (int mt = 0; mt < 4; mt++) {
            const int row = mt * 16 + lc;
            #pragma unroll
            for (int ks = 0; ks < 2; ks++) {
                const int slot = (ks * 4 + q) ^ (lc & 7);
                afr[mt][ks] = *(const bf16x8*)(&Alds[w][row * 64 + slot * 8]);
            }
        }
        // B frags from LDS: slot = oc*8 + (kc ^ (oc&7)), oc = nt*16+lc, kc = ks*4+q
        bf16x8 bfr[4][2];
        #pragma unroll
        for (int nt = 0; nt < 4; nt++) {
            const int oc = nt * 16 + lc;
            #pragma unroll
            for (int ks = 0; ks < 2; ks++) {
                const int slot = oc * 8 + ((ks * 4 + q) ^ (oc & 7));
                bfr[nt][ks] = *(const bf16x8*)(&Blds[off & 1][slot * 8]);
            }
        }

        #pragma unroll
        for (int ks = 0; ks < 2; ks++)
            #pragma unroll
            for (int mt = 0; mt < 4; mt++)
                #pragma unroll
                for (int nt = 0; nt < 4; nt++)
                    acc[mt][nt] = __builtin_amdgcn_mfma_f32_16x16x32_bf16(
                        afr[mt][ks], bfr[nt][ks], acc[mt][nt], 0, 0, 0);

        __syncthreads();   // buf[off&1] consumed by all; prefetch for off+1 has landed
    }

    #pragma unroll
    for (int nt = 0; nt < 4; nt++) {
        const int oc = nt * 16 + lc;
        const float bias = b2[oc];
        #pragma unroll
        for (int mt = 0; mt < 4; mt++) {
            const int pt = pw + mt * 16 + q * 4;
            #pragma unroll
            for (int r = 0; r < 4; r++) {
                if (pt + r < NPTS) {
                    float v = acc[mt][nt][r] + bias;
                    g[(size_t)(pt + r) * 64 + oc] = __float2bfloat16(v > 0.f ? v : 0.f);
                }
            }
        }
    }
}

// ---------------- K3: fused MLP via MFMA. block = 64 points, 4 waves split N ----------------
__global__ __launch_bounds__(256) void mlp_mfma(
    const __hip_bfloat16* __restrict__ g,
    const short* __restrict__ w1b, const float* __restrict__ bp1,
    const short* __restrict__ w2b, const float* __restrict__ bp2,
    const short* __restrict__ w3b, const float* __restrict__ bp3,
    const float* __restrict__ wp4, const float* __restrict__ bp4,
    float* __restrict__ out)
{
    __shared__ short bufA[64 * 256];   // 32 KB: X, then H2
    __shared__ short bufB[64 * 256];   // 32 KB: H1; then fp32 H3 overlay
    float* h3f = (float*)bufB;

    const int tid = threadIdx.x;
    const int pb = blockIdx.x * 64;
    const int w = tid >> 6, lane = tid & 63;
    const int q = lane >> 4, lc = lane & 15;

    const short* gs = (const short*)g;
    #pragma unroll
    for (int it = 0; it < 2; it++) {
        int idx = it * 256 + tid;
        int r = idx >> 3, c = idx & 7;
        int4 v = *(const int4*)(gs + (size_t)(pb + r) * 64 + c * 8);
        *(int4*)(&bufA[r * 256 + (c ^ (r & 7)) * 8]) = v;
    }
    __syncthreads();

    // L1: 64 -> 256, relu
    {
        floatx4 acc[4][4];
        #pragma unroll
        for (int mt = 0; mt < 4; mt++)
            #pragma unroll
            for (int nt = 0; nt < 4; nt++)
                acc[mt][nt] = (floatx4){0.f, 0.f, 0.f, 0.f};

        #pragma unroll
        for (int ks = 0; ks < 2; ks++) {
            bf16x8 bfr[4];
            #pragma unroll
            for (int nt = 0; nt < 4; nt++)
                bfr[nt] = *(const bf16x8*)(w1b + (w * 64 + nt * 16 + lc) * 64 + ks * 32 + q * 8);
            const int c = ks * 4 + q;
            #pragma unroll
            for (int mt = 0; mt < 4; mt++) {
                const int m = mt * 16 + lc;
                bf16x8 afr = *(const bf16x8*)(&bufA[m * 256 + (c ^ (m & 7)) * 8]);
                #pragma unroll
                for (int nt = 0; nt < 4; nt++)
                    acc[mt][nt] = __builtin_amdgcn_mfma_f32_16x16x32_bf16(afr, bfr[nt], acc[mt][nt], 0, 0, 0);
            }
        }
        float bias[4];
        #pragma unroll
        for (int nt = 0; nt < 4; nt++) bias[nt] = bp1[w * 64 + nt * 16 + lc];
        #pragma unroll
        for (int mt = 0; mt < 4; mt++)
            #pragma unroll
            for (int nt = 0; nt < 4; nt++) {
                const int col = w * 64 + nt * 16 + lc;
                #pragma unroll
                for (int r = 0; r < 4; r++) {
                    const int m = mt * 16 + q * 4 + r;
                    float v = acc[mt][nt][r] + bias[nt];
                    v = v > 0.f ? v : 0.f;
                    bufB[m * 256 + (((col >> 3) ^ (m & 7)) * 8 + (col & 7))] = f2bf(v);
                }
            }
    }
    __syncthreads();

    // L2: 256 -> 256, relu
    {
        floatx4 acc[4][4];
        #pragma unroll
        for (int mt = 0; mt < 4; mt++)
            #pragma unroll
            for (int nt = 0; nt < 4; nt++)
                acc[mt][nt] = (floatx4){0.f, 0.f, 0.f, 0.f};

        #pragma unroll
        for (int ks = 0; ks < 8; ks++) {
            bf16x8 bfr[4];
            #pragma unroll
            for (int nt = 0; nt < 4; nt++)
                bfr[nt] = *(const bf16x8*)(w2b + (w * 64 + nt * 16 + lc) * 256 + ks * 32 + q * 8);
            const int c = ks * 4 + q;
            #pragma unroll
            for (int mt = 0; mt < 4; mt++) {
                const int m = mt * 16 + lc;
                const int pc = (c & 24) | ((c & 7) ^ (m & 7));
                bf16x8 afr = *(const bf16x8*)(&bufB[m * 256 + pc * 8]);
                #pragma unroll
                for (int nt = 0; nt < 4; nt++)
                    acc[mt][nt] = __builtin_amdgcn_mfma_f32_16x16x32_bf16(afr, bfr[nt], acc[mt][nt], 0, 0, 0);
            }
        }
        float bias[4];
        #pragma unroll
        for (int nt = 0; nt < 4; nt++) bias[nt] = bp2[w * 64 + nt * 16 + lc];
        __syncthreads();
        #pragma unroll
        for (int mt = 0; mt < 4; mt++)
            #pragma unroll
            for (int nt = 0; nt < 4; nt++) {
                const int col = w * 64 + nt * 16 + lc;
                #pragma unroll
                for (int r = 0; r < 4; r++) {
                    const int m = mt * 16 + q * 4 + r;
                    float v = acc[mt][nt][r] + bias[nt];
                    v = v > 0.f ? v : 0.f;
                    bufA[m * 256 + (((col >> 3) ^ (m & 7)) * 8 + (col & 7))] = f2bf(v);
                }
            }
    }
    __syncthreads();

    // L3: 256 -> 64
    {
        floatx4 acc[4];
        #pragma unroll
        for (int mt = 0; mt < 4; mt++) acc[mt] = (floatx4){0.f, 0.f, 0.f, 0.f};

        #pragma unroll
        for (int ks = 0; ks < 8; ks++) {
            bf16x8 bfr = *(const bf16x8*)(w3b + (w * 16 + lc) * 256 + ks * 32 + q * 8);
            const int c = ks * 4 + q;
            #pragma unroll
            for (int mt = 0; mt < 4; mt++) {
                const int m = mt * 16 + lc;
                const int pc = (c & 24) | ((c & 7) ^ (m & 7));
                bf16x8 afr = *(const bf16x8*)(&bufA[m * 256 + pc * 8]);
                acc[mt] = __builtin_amdgcn_mfma_f32_16x16x32_bf16(afr, bfr, acc[mt], 0, 0, 0);
            }
        }
        const float bias = bp3[w * 16 + lc];
        const int col = w * 16 + lc;
        __syncthreads();
        #pragma unroll
        for (int mt = 0; mt < 4; mt++)
            #pragma unroll
            for (int r = 0; r < 4; r++) {
                const int m = mt * 16 + q * 4 + r;
                h3f[m * 65 + col] = acc[mt][r] + bias;
            }
    }
    __syncthreads();

    // L4: 64 -> 6
    for (int e = tid; e < 384; e += 256) {
        int c = e >> 6, p = e & 63;
        float a = bp4[c];
        const float* wr = wp4 + c * 64;
        const float* xr = h3f + p * 65;
        #pragma unroll 8
        for (int k = 0; k < 64; k++) a += wr[k] * xr[k];
        out[(size_t)c * NPTS + pb + p] = a;
    }
}

extern "C" void kernel_launch(void* const* d_in, const int* in_sizes, int n_in,
                              void* d_out, int out_size, void* d_ws, size_t ws_size,
                              hipStream_t stream) {
    const float* img = (const float*)d_in[0];
    const int* c0 = (const int*)d_in[1];
    const int* c1 = (const int*)d_in[2];
    const int* c2 = (const int*)d_in[3];
    const float* w_enc1 = (const float*)d_in[4];
    const float* b_enc1 = (const float*)d_in[5];
    const float* w_enc2 = (const float*)d_in[6];
    const float* b_enc2 = (const float*)d_in[7];
    const float* w_p1 = (const float*)d_in[8];
    const float* b_p1 = (const float*)d_in[9];
    const float* w_p2 = (const float*)d_in[10];
    const float* b_p2 = (const float*)d_in[11];
    const float* w_p3 = (const float*)d_in[12];
    const float* b_p3 = (const float*)d_in[13];
    const float* w_p4 = (const float*)d_in[14];
    const float* b_p4 = (const float*)d_in[15];
    float* out = (float*)d_out;

    short* f1b = (short*)d_ws;                       // 32,768,000
    short* wpb = f1b + (size_t)VOX * 64;             // 110592
    short* w1b = wpb + 110592;                       // 16384
    short* w2b = w1b + 16384;                        // 65536
    short* w3b = w2b + 65536;                        // 16384
    short* gb  = w3b + 16384;                        // 12,800,000
    short* img_t = gb + (size_t)NPTS * 64;           // 16,384,000
    short* wc1 = img_t + (size_t)VOX * 32;           // 55296
    short* zeros = wc1 + 55296;                      // 64 shorts (128 B zero source)

    hipMemsetAsync(zeros, 0, 128, stream);
    convert_weights<<<(264192 + 255) / 256, 256, 0, stream>>>(
        w_enc2, w_p1, w_p2, w_p3, w_enc1, wpb, w1b, w2b, w3b, wc1);
    transpose_img<<<(VOX + 255) / 256, 256, 0, stream>>>(img, img_t);
    conv1_mfma<<<DD * DD, 256, 0, stream>>>(img_t, wc1, b_enc1, zeros, f1b);
    conv2_mfma<<<(NPTS + 255) / 256, 256, 0, stream>>>(
        f1b, wpb, b_enc2, c0, c1, c2, zeros, (__hip_bfloat16*)gb);
    mlp_mfma<<<NPTS / 64, 256, 0, stream>>>(
        (const __hip_bfloat16*)gb, w1b, b_p1, w2b, b_p2, w3b, b_p3, w_p4, b_p4, out);
}